// Round 10
// baseline (308.951 us; speedup 1.0000x reference)
//
#include <hip/hip_runtime.h>

typedef __attribute__((ext_vector_type(4))) float f32x4;
typedef __attribute__((ext_vector_type(8))) short s16x8;
typedef __attribute__((ext_vector_type(4))) unsigned short u16x4;
typedef __attribute__((ext_vector_type(8))) unsigned short u16x8;

#define DEVINL __device__ __forceinline__

constexpr int Bb = 2;
constexpr int Ss = 2048;
constexpr int Hh = 2048;
constexpr int NH = 16;
constexpr int HD = 128;
constexpr float ATT_SCALE = 0.08838834764831845f;   // 128^-0.5
constexpr float CEXP = ATT_SCALE * 1.44269504089f;  // scale * log2(e)
constexpr float INV_SCALE = 11.313708498984761f;    // 1/scale
constexpr float RAW_THR = 90.50966799f;             // 8/scale (defer-max threshold)

DEVINL unsigned short f2bf(float f) {
    unsigned u = __float_as_uint(f);
    u += 0x7FFFu + ((u >> 16) & 1u);
    return (unsigned short)(u >> 16);
}
DEVINL float bf2f(unsigned short h) { return __uint_as_float(((unsigned)h) << 16); }
DEVINL float fexp2(float x) { return __builtin_amdgcn_exp2f(x); }

// global -> LDS direct (16B per lane). Dest must be linear in lane order.
DEVINL void gl16(const void* g, void* l) {
    __builtin_amdgcn_global_load_lds((const __attribute__((address_space(1))) void*)g,
                                     (__attribute__((address_space(3))) void*)l, 16, 0, 0);
}

// ---------------- mask zero-scan ----------------
__global__ void zero_flag_k(int* f) { if (threadIdx.x == 0) *f = 0; }

__global__ void scan_mask_k(const float* __restrict__ m, int* __restrict__ flag) {
    size_t i = ((size_t)blockIdx.x * 256 + threadIdx.x) * 4;
    f32x4 v = *(const f32x4*)(m + i);
    int any = (v[0] != 0.f) || (v[1] != 0.f) || (v[2] != 0.f) || (v[3] != 0.f);
    if (__any(any)) { if ((threadIdx.x & 63) == 0) atomicOr(flag, 1); }
}

// ---------------- fp32 -> bf16 convert (hidden) ----------------
__global__ void convH_k(const float* __restrict__ x, unsigned short* __restrict__ y) {
    size_t i = (size_t)blockIdx.x * 256 + threadIdx.x;
    f32x4 a = *(const f32x4*)(x + i * 8);
    f32x4 b = *(const f32x4*)(x + i * 8 + 4);
    u16x8 o;
    o[0] = f2bf(a[0]); o[1] = f2bf(a[1]); o[2] = f2bf(a[2]); o[3] = f2bf(a[3]);
    o[4] = f2bf(b[0]); o[5] = f2bf(b[1]); o[6] = f2bf(b[2]); o[7] = f2bf(b[3]);
    *(u16x8*)(y + i * 8) = o;
}

// ---------------- fp32 -> bf16 transpose (weights: W[R][C] -> Wt[C][R]) ----------------
__global__ void convT_k(const float* __restrict__ W, unsigned short* __restrict__ Wt,
                        int R, int C) {
    __shared__ float tile[32][33];
    int c0 = blockIdx.x * 32, r0 = blockIdx.y * 32;
    int t = threadIdx.x;
    int rr = t >> 3, cc = (t & 7) * 4;
    f32x4 v = *(const f32x4*)(W + (size_t)(r0 + rr) * C + c0 + cc);
    tile[rr][cc + 0] = v[0]; tile[rr][cc + 1] = v[1];
    tile[rr][cc + 2] = v[2]; tile[rr][cc + 3] = v[3];
    __syncthreads();
    u16x4 o;
    o[0] = f2bf(tile[cc + 0][rr]); o[1] = f2bf(tile[cc + 1][rr]);
    o[2] = f2bf(tile[cc + 2][rr]); o[3] = f2bf(tile[cc + 3][rr]);
    *(u16x4*)(Wt + (size_t)(c0 + rr) * R + r0 + cc) = o;
}

// ================== 256x256 8-phase GEMM, conflict-free LDS (R9 state) ==================
#define PH(buf, kh, ih, sbuf, sunit, st, vm)                                      \
  {                                                                               \
    const char* Ar = lds + (buf)*65536;                                           \
    const char* Br = Ar + 32768;                                                  \
    s16x8 af[4];                                                                  \
    if ((ih) == 0) {                                                              \
      _Pragma("unroll")                                                           \
      for (int j = 0; j < 4; ++j) {                                               \
        int row = wn*64 + j*16 + lr;                                              \
        bfr[j] = *(const s16x8*)(Br + row*128 + (((kh)*64 + lg*16) ^ ((row&7)<<4))); \
      }                                                                           \
    }                                                                             \
    _Pragma("unroll")                                                             \
    for (int i = 0; i < 4; ++i) {                                                 \
      int row = wm*128 + (ih)*64 + i*16 + lr;                                     \
      af[i] = *(const s16x8*)(Ar + row*128 + (((kh)*64 + lg*16) ^ ((row&7)<<4))); \
    }                                                                             \
    STG(sbuf, sunit, st);                                                         \
    __builtin_amdgcn_s_barrier();                                                 \
    asm volatile("s_waitcnt lgkmcnt(0)" ::: "memory");                            \
    __builtin_amdgcn_s_setprio(1);                                                \
    _Pragma("unroll")                                                             \
    for (int i = 0; i < 4; ++i)                                                   \
      _Pragma("unroll")                                                           \
      for (int j = 0; j < 4; ++j)                                                 \
        acc[(ih)*4 + i][j] = __builtin_amdgcn_mfma_f32_16x16x32_bf16(             \
            af[i], bfr[j], acc[(ih)*4 + i][j], 0, 0, 0);                          \
    __builtin_amdgcn_s_setprio(0);                                                \
    if ((vm) == 2) { asm volatile("s_waitcnt vmcnt(2)" ::: "memory"); }           \
    if ((vm) == 4) { asm volatile("s_waitcnt vmcnt(4)" ::: "memory"); }           \
    __builtin_amdgcn_s_barrier();                                                 \
  }

template<int MODE>
__global__ __launch_bounds__(512, 2)
void gemm256_k(const unsigned short* __restrict__ A, const unsigned short* __restrict__ Bt,
               float* __restrict__ Cf, unsigned short* __restrict__ Cb,
               int M, int N, int K) {
    __shared__ char lds[131072];
    int t = threadIdx.x, w = t >> 6, ln = t & 63, lr = ln & 15, lg = ln >> 4;
    int wm = w >> 2, wn = w & 3;
    int f = blockIdx.x, cpx = gridDim.x >> 3;
    int s = (f & 7) * cpx + (f >> 3);      // bijective XCD swizzle (grid % 8 == 0)
    int nbn = N >> 8;
    int nb = s % nbn, mb = s / nbn;
    int m0 = mb * 256, n0 = nb * 256;
    const char* Ab = (const char*)A;
    const char* Bbp = (const char*)Bt;

    f32x4 acc[8][4];
#pragma unroll
    for (int i = 0; i < 8; ++i)
#pragma unroll
        for (int j = 0; j < 4; ++j) { acc[i][j][0] = 0.f; acc[i][j][1] = 0.f; acc[i][j][2] = 0.f; acc[i][j][3] = 0.f; }

    auto STG = [&](int sbuf, int unit, int kt) {
        int isB = unit >> 1;
        const char* src = isB ? Bbp : Ab;
        int rbase = isB ? n0 : m0;
        char* reg = lds + sbuf * 65536 + isB * 32768;
        size_t kb = ((size_t)kt * 64) * 2;
#pragma unroll
        for (int rr = 0; rr < 2; ++rr) {
            int rowbase = isB ? ((unit & 1) * 128 + rr * 64)
                              : (rr * 128 + (unit & 1) * 64);
            int row = rowbase + (t >> 3);
            int slot = (t & 7) ^ (row & 7);
            gl16(src + ((size_t)(rbase + row) * K) * 2 + kb + slot * 16,
                 reg + rowbase * 128 + t * 16);
        }
    };

    const int NT = K >> 6;
    STG(0, 0, 0); STG(0, 2, 0); STG(0, 3, 0); STG(0, 1, 0);
    STG(1, 0, 1);
    asm volatile("s_waitcnt vmcnt(2)" ::: "memory");
    __builtin_amdgcn_s_barrier();

    s16x8 bfr[4];
    for (int it = 0; it < (NT >> 1); ++it) {
        int e = it * 2;
        int e2 = (e + 2 < NT) ? e + 2 : e;
        int e3 = (e + 3 < NT) ? e + 3 : e + 1;
        PH(0, 0, 0,  1, 2, e + 1, 4)
        PH(0, 0, 1,  1, 3, e + 1, -1)
        PH(0, 1, 0,  1, 1, e + 1, -1)
        PH(0, 1, 1,  0, 0, e2,    4)
        PH(1, 0, 0,  0, 2, e2,    4)
        PH(1, 0, 1,  0, 3, e2,   -1)
        PH(1, 1, 0,  0, 1, e2,   -1)
        PH(1, 1, 1,  1, 0, e3,    4)
    }
    asm volatile("s_waitcnt vmcnt(0)" ::: "memory");

    if (MODE == 0 && n0 < 4096 && (wn & 1) == 0) {
        float invf = fexp2((float)lr * -0.83048202372f); // 10000^(-lr/16)
#pragma unroll
        for (int i = 0; i < 8; ++i)
#pragma unroll
            for (int r = 0; r < 4; ++r) {
                int srow = (m0 + wm * 128 + i * 16 + lg * 4 + r) & (Ss - 1);
                float sn, cs;
                sincosf((float)srow * invf, &sn, &cs);
                float x1 = acc[i][0][r], x2 = acc[i][1][r];
                acc[i][0][r] = x1 * cs - x2 * sn;
                acc[i][1][r] = x2 * cs + x1 * sn;
            }
    }

#pragma unroll
    for (int i = 0; i < 8; ++i)
#pragma unroll
        for (int j = 0; j < 4; ++j)
#pragma unroll
            for (int r = 0; r < 4; ++r) {
                int gr = m0 + wm * 128 + i * 16 + lg * 4 + r;
                int gc = n0 + wn * 64 + j * 16 + lr;
                float vv = acc[i][j][r];
                if (MODE == 1) Cf[(size_t)gr * N + gc] = vv;
                else           Cb[(size_t)gr * N + gc] = f2bf(vv);
            }
}

// ================== 128x128 GEMM (out-proj; proven R3/R6 kernel) ==================
template<int MODE>
__global__ __launch_bounds__(256)
void gemm_bt_k(const unsigned short* __restrict__ A, const unsigned short* __restrict__ Bt,
               float* __restrict__ Cf, unsigned short* __restrict__ Cb,
               int M, int N, int K) {
    __shared__ char lds[128 * 64 * 2 * 2];
    char* As = lds;
    char* Bs = lds + 128 * 64 * 2;
    int t = threadIdx.x, w = t >> 6, ln = t & 63, lr = ln & 15, lg = ln >> 4;
    int f = blockIdx.x;
    int cpx = gridDim.x >> 3;
    int s = (f & 7) * cpx + (f >> 3);
    int nbn = N >> 7;
    int nb = s % nbn, mb = s / nbn;
    int m0 = mb * 128, n0 = nb * 128;
    int wr = w >> 1, wc = w & 1;
    const char* Abt = (const char*)A;
    const char* Bbt = (const char*)Bt;

    f32x4 acc[4][4];
#pragma unroll
    for (int i = 0; i < 4; ++i)
#pragma unroll
        for (int j = 0; j < 4; ++j) { acc[i][j][0] = 0.f; acc[i][j][1] = 0.f; acc[i][j][2] = 0.f; acc[i][j][3] = 0.f; }

    for (int k0 = 0; k0 < K; k0 += 64) {
        __syncthreads();
#pragma unroll
        for (int vv = 0; vv < 4; ++vv) {
            int ci = vv * 256 + t;
            int row = ci >> 3, cb = (ci & 7) << 4;
            int sc = cb ^ ((row & 7) << 4);
            gl16(Abt + ((size_t)(m0 + row) * K + k0) * 2 + sc, As + ci * 16);
            gl16(Bbt + ((size_t)(n0 + row) * K + k0) * 2 + sc, Bs + ci * 16);
        }
        __syncthreads();
#pragma unroll
        for (int kc = 0; kc < 2; ++kc) {
            s16x8 af[4], bfr[4];
#pragma unroll
            for (int i = 0; i < 4; ++i) {
                int rowa = wr * 64 + i * 16 + lr;
                af[i] = *(const s16x8*)(As + rowa * 128 + ((kc * 64 + lg * 16) ^ ((rowa & 7) << 4)));
                int rowb = wc * 64 + i * 16 + lr;
                bfr[i] = *(const s16x8*)(Bs + rowb * 128 + ((kc * 64 + lg * 16) ^ ((rowb & 7) << 4)));
            }
#pragma unroll
            for (int i = 0; i < 4; ++i)
#pragma unroll
                for (int j = 0; j < 4; ++j)
                    acc[i][j] = __builtin_amdgcn_mfma_f32_16x16x32_bf16(af[i], bfr[j], acc[i][j], 0, 0, 0);
        }
    }
#pragma unroll
    for (int i = 0; i < 4; ++i)
#pragma unroll
        for (int j = 0; j < 4; ++j)
#pragma unroll
            for (int r = 0; r < 4; ++r) {
                int gr = m0 + wr * 64 + i * 16 + lg * 4 + r;
                int gc = n0 + wc * 64 + j * 16 + lr;
                float vv = acc[i][j][r];
                if (MODE == 1) Cf[(size_t)gr * N + gc] = vv;
                else           Cb[(size_t)gr * N + gc] = f2bf(vv);
            }
}

// ---------------- V transpose: qkv v-part -> Vt[bh][d][s] ----------------
__global__ void vtrans_k(const unsigned short* __restrict__ qkv, unsigned short* __restrict__ Vt) {
    __shared__ unsigned short tile[64][40];
    int bh = blockIdx.x; int b = bh >> 4, h = bh & 15;
    int s0 = blockIdx.y * 64, d0 = blockIdx.z * 32;
    int t = threadIdx.x;
    int r = t >> 2, c8 = (t & 3) * 8;
    u16x8 v = *(const u16x8*)(qkv + ((size_t)(b * Ss + s0 + r)) * 6144 + 4096 + h * 128 + d0 + c8);
#pragma unroll
    for (int e = 0; e < 8; ++e) tile[r][c8 + e] = v[e];
    __syncthreads();
    int dr = t >> 3, sc = (t & 7) * 8;
    u16x8 o;
#pragma unroll
    for (int e = 0; e < 8; ++e) o[e] = tile[sc + e][dr];
    *(u16x8*)(Vt + ((size_t)bh * HD + d0 + dr) * Ss + s0 + sc) = o;
}

// ---------------- flash attention (R10: double-buffered K/V, overlapped staging) -------
// 512 blocks (32 bh x 16 qt), 512 thr = 8 waves x 16 q-rows, KVBLK=64.
// LDS 80 KB -> 2 blocks/CU, all 512 blocks co-resident.
// Per tile: issue next tile's 4 gl16 FIRST (latency hides under compute),
// compute QK/softmax/PV from current buffer, then vmcnt(0) (free) + 1 barrier.
__global__ __launch_bounds__(512)
void attn_k(const unsigned short* __restrict__ qkv, const unsigned short* __restrict__ Vt,
            const float* __restrict__ mask, unsigned short* __restrict__ ctxb,
            const int* __restrict__ flag) {
    __shared__ char ldsK[2][16384];            // [64 kk][128 d] bf16, swizzled
    __shared__ char ldsV[2][16384];            // [128 d][64 kk] bf16, swizzled
    __shared__ unsigned short ldsP[8][1024];   // per-wave P [16 q][64 kk], swizzled
    int f = blockIdx.x;
    int swzb = (f & 7) * 64 + (f >> 3);        // XCD swizzle
    int bh = swzb >> 4, qt = swzb & 15;
    int b = bh >> 4, h = bh & 15;
    int t = threadIdx.x, w = t >> 6, ln = t & 63, lr = ln & 15, lg = ln >> 4;
    int useMask = *flag;
    int qw0 = qt * 128 + w * 16;
    const char* qkvB = (const char*)qkv;
    const char* VtB = (const char*)Vt;

    auto STAGE = [&](int buf, int kk0s) {
#pragma unroll
        for (int c = 0; c < 2; ++c) {
            int ci = c * 512 + t;
            int krow = ci >> 4, kcb = (ci & 15) << 4;
            gl16(qkvB + (((size_t)(b * Ss + kk0s + krow)) * 6144 + 2048 + h * 128) * 2 + (kcb ^ ((krow & 7) << 4)),
                 ldsK[buf] + ci * 16);
            int vrow = ci >> 3, vcb = (ci & 7) << 4;
            gl16(VtB + (((size_t)(bh * 128 + vrow)) * 2048 + kk0s) * 2 + (vcb ^ ((vrow & 7) << 4)),
                 ldsV[buf] + ci * 16);
        }
    };

    s16x8 qf[4];
    size_t qbase = ((size_t)(b * Ss + qw0 + lr)) * 6144 + h * 128;
#pragma unroll
    for (int kc = 0; kc < 4; ++kc) qf[kc] = *(const s16x8*)(qkv + qbase + kc * 32 + lg * 8);

    float mr = -3e38f, lsum = 0.f;
    f32x4 ctxa[8];
#pragma unroll
    for (int dn = 0; dn < 8; ++dn) { ctxa[dn][0] = 0.f; ctxa[dn][1] = 0.f; ctxa[dn][2] = 0.f; ctxa[dn][3] = 0.f; }
    const float* mrow = mask + (size_t)b * Ss * Ss;

    // prologue: stage tile 0 into buf 0
    STAGE(0, 0);
    asm volatile("s_waitcnt vmcnt(0)" ::: "memory");
    __builtin_amdgcn_s_barrier();

    for (int tix = 0; tix < 32; ++tix) {
        int kk0 = tix * 64;
        int cur = tix & 1;
        if (kk0 + 64 < Ss) STAGE(cur ^ 1, kk0 + 64);   // uniform branch

        f32x4 st[4];
#pragma unroll
        for (int n = 0; n < 4; ++n) {
            f32x4 sacc = {0.f, 0.f, 0.f, 0.f};
            const char* kb = ldsK[cur] + (n * 16 + lr) * 256;
            int sw = (lr & 7) << 4;
            s16x8 kf0 = *(const s16x8*)(kb + ((0 * 64 + lg * 16) ^ sw));
            s16x8 kf1 = *(const s16x8*)(kb + ((1 * 64 + lg * 16) ^ sw));
            s16x8 kf2 = *(const s16x8*)(kb + ((2 * 64 + lg * 16) ^ sw));
            s16x8 kf3 = *(const s16x8*)(kb + ((3 * 64 + lg * 16) ^ sw));
            __builtin_amdgcn_s_setprio(1);
            sacc = __builtin_amdgcn_mfma_f32_16x16x32_bf16(kf0, qf[0], sacc, 0, 0, 0);
            sacc = __builtin_amdgcn_mfma_f32_16x16x32_bf16(kf1, qf[1], sacc, 0, 0, 0);
            sacc = __builtin_amdgcn_mfma_f32_16x16x32_bf16(kf2, qf[2], sacc, 0, 0, 0);
            sacc = __builtin_amdgcn_mfma_f32_16x16x32_bf16(kf3, qf[3], sacc, 0, 0, 0);
            __builtin_amdgcn_s_setprio(0);
            st[n] = sacc;
        }
        if (useMask) {
#pragma unroll
            for (int n = 0; n < 4; ++n)
#pragma unroll
                for (int r = 0; r < 4; ++r)
                    st[n][r] += mrow[(size_t)(qw0 + lr) * Ss + kk0 + n * 16 + lg * 4 + r] * INV_SCALE;
        }
        float pmax = st[0][0];
#pragma unroll
        for (int n = 0; n < 4; ++n)
#pragma unroll
            for (int r = 0; r < 4; ++r) pmax = fmaxf(pmax, st[n][r]);
        pmax = fmaxf(pmax, __shfl_xor(pmax, 16));
        pmax = fmaxf(pmax, __shfl_xor(pmax, 32));
        bool need = pmax > mr + RAW_THR;
        if (__any(need)) {
            float mn = fmaxf(mr, pmax);
            float al = fexp2((mr - mn) * CEXP);
            mr = mn;
            lsum *= al;
            float a0 = __shfl(al, lg * 4 + 0), a1 = __shfl(al, lg * 4 + 1);
            float a2 = __shfl(al, lg * 4 + 2), a3 = __shfl(al, lg * 4 + 3);
#pragma unroll
            for (int dn = 0; dn < 8; ++dn) {
                ctxa[dn][0] *= a0; ctxa[dn][1] *= a1; ctxa[dn][2] *= a2; ctxa[dn][3] *= a3;
            }
        }
        float mC = mr * CEXP;
        float rs = 0.f;
        u16x4 pk[4];
#pragma unroll
        for (int n = 0; n < 4; ++n)
#pragma unroll
            for (int r = 0; r < 4; ++r) {
                float p = fexp2(st[n][r] * CEXP - mC);
                rs += p;
                pk[n][r] = f2bf(p);
            }
        rs += __shfl_xor(rs, 16);
        rs += __shfl_xor(rs, 32);
        lsum += rs;
        char* pw = (char*)ldsP[w];
        int swp = (lr & 7) << 4;
#pragma unroll
        for (int n = 0; n < 4; ++n)
            *(u16x4*)(pw + lr * 128 + ((32 * n + 8 * lg) ^ swp)) = pk[n];
        asm volatile("s_waitcnt lgkmcnt(0)" ::: "memory");
        s16x8 pa[2];
#pragma unroll
        for (int c2 = 0; c2 < 2; ++c2)
            pa[c2] = *(const s16x8*)(pw + lr * 128 + ((64 * c2 + 16 * lg) ^ swp));
#pragma unroll
        for (int dn = 0; dn < 8; ++dn) {
            const char* vb = ldsV[cur] + (dn * 16 + lr) * 128;
            s16x8 vf0 = *(const s16x8*)(vb + ((0 * 64 + lg * 16) ^ swp));
            s16x8 vf1 = *(const s16x8*)(vb + ((1 * 64 + lg * 16) ^ swp));
            __builtin_amdgcn_s_setprio(1);
            ctxa[dn] = __builtin_amdgcn_mfma_f32_16x16x32_bf16(pa[0], vf0, ctxa[dn], 0, 0, 0);
            ctxa[dn] = __builtin_amdgcn_mfma_f32_16x16x32_bf16(pa[1], vf1, ctxa[dn], 0, 0, 0);
            __builtin_amdgcn_s_setprio(0);
        }
        // next tile's loads landed long ago (issued before compute): drain + 1 barrier
        asm volatile("s_waitcnt vmcnt(0)" ::: "memory");
        __builtin_amdgcn_s_barrier();
    }
    float l0 = 1.f / __shfl(lsum, lg * 4 + 0), l1 = 1.f / __shfl(lsum, lg * 4 + 1);
    float l2 = 1.f / __shfl(lsum, lg * 4 + 2), l3 = 1.f / __shfl(lsum, lg * 4 + 3);
#pragma unroll
    for (int dn = 0; dn < 8; ++dn) {
        size_t base = ((size_t)(b * Ss + qw0)) * Hh + h * 128 + dn * 16 + lr;
        ctxb[base + (size_t)(lg * 4 + 0) * Hh] = f2bf(ctxa[dn][0] * l0);
        ctxb[base + (size_t)(lg * 4 + 1) * Hh] = f2bf(ctxa[dn][1] * l1);
        ctxb[base + (size_t)(lg * 4 + 2) * Hh] = f2bf(ctxa[dn][2] * l2);
        ctxb[base + (size_t)(lg * 4 + 3) * Hh] = f2bf(ctxa[dn][3] * l3);
    }
}

extern "C" void kernel_launch(void* const* d_in, const int* in_sizes, int n_in,
                              void* d_out, int out_size, void* d_ws, size_t ws_size,
                              hipStream_t stream) {
    (void)in_sizes; (void)n_in; (void)out_size; (void)ws_size;
    const float* hidden = (const float*)d_in[0];
    const float* mask   = (const float*)d_in[1];
    const float* Wqkv   = (const float*)d_in[2];
    const float* Wout   = (const float*)d_in[3];
    float* out = (float*)d_out;

    char* ws = (char*)d_ws;
    size_t off = 0;
    auto alloc = [&](size_t bytes) { char* p = ws + off; off += (bytes + 255) & ~(size_t)255; return p; };
    unsigned short* hbf   = (unsigned short*)alloc((size_t)8388608 * 2);   // hidden bf16; later aliased as ctx
    unsigned short* wqkvT = (unsigned short*)alloc((size_t)12582912 * 2);  // (6144,2048)
    unsigned short* woutT = (unsigned short*)alloc((size_t)4194304 * 2);   // (2048,2048)
    unsigned short* qkv   = (unsigned short*)alloc((size_t)25165824 * 2);  // (4096,6144)
    unsigned short* Vt    = (unsigned short*)alloc((size_t)8388608 * 2);   // (32,128,2048)
    int* flag             = (int*)alloc(256);
    unsigned short* ctx = hbf; // alias: hidden bf16 dead after QKV GEMM

    zero_flag_k<<<1, 64, 0, stream>>>(flag);
    scan_mask_k<<<2048, 256, 0, stream>>>(mask, flag);
    convH_k<<<4096, 256, 0, stream>>>(hidden, hbf);
    convT_k<<<dim3(192, 64), 256, 0, stream>>>(Wqkv, wqkvT, 2048, 6144);
    convT_k<<<dim3(64, 64), 256, 0, stream>>>(Wout, woutT, 2048, 2048);
    gemm256_k<0><<<384, 512, 0, stream>>>(hbf, wqkvT, nullptr, qkv, 4096, 6144, 2048);
    vtrans_k<<<dim3(32, 32, 4), 256, 0, stream>>>(qkv, Vt);
    attn_k<<<512, 512, 0, stream>>>(qkv, Vt, mask, ctx, flag);
    gemm_bt_k<1><<<512, 256, 0, stream>>>(ctx, woutT, out, nullptr, 4096, 2048, 2048);
}

// Round 11
// 301.583 us; speedup vs baseline: 1.0244x; 1.0244x over previous
//
#include <hip/hip_runtime.h>

typedef __attribute__((ext_vector_type(4))) float f32x4;
typedef __attribute__((ext_vector_type(8))) short s16x8;
typedef __attribute__((ext_vector_type(4))) unsigned short u16x4;
typedef __attribute__((ext_vector_type(8))) unsigned short u16x8;

#define DEVINL __device__ __forceinline__

constexpr int Bb = 2;
constexpr int Ss = 2048;
constexpr int Hh = 2048;
constexpr int NH = 16;
constexpr int HD = 128;
constexpr float ATT_SCALE = 0.08838834764831845f;   // 128^-0.5
constexpr float CEXP = ATT_SCALE * 1.44269504089f;  // scale * log2(e)
constexpr float INV_SCALE = 11.313708498984761f;    // 1/scale
constexpr float RAW_THR = 90.50966799f;             // 8/scale (defer-max threshold)

DEVINL unsigned short f2bf(float f) {
    unsigned u = __float_as_uint(f);
    u += 0x7FFFu + ((u >> 16) & 1u);
    return (unsigned short)(u >> 16);
}
DEVINL float bf2f(unsigned short h) { return __uint_as_float(((unsigned)h) << 16); }
DEVINL float fexp2(float x) { return __builtin_amdgcn_exp2f(x); }

// global -> LDS direct (16B per lane). Dest must be linear in lane order.
DEVINL void gl16(const void* g, void* l) {
    __builtin_amdgcn_global_load_lds((const __attribute__((address_space(1))) void*)g,
                                     (__attribute__((address_space(3))) void*)l, 16, 0, 0);
}

// ---------------- mask zero-scan ----------------
__global__ void zero_flag_k(int* f) { if (threadIdx.x == 0) *f = 0; }

__global__ void scan_mask_k(const float* __restrict__ m, int* __restrict__ flag) {
    size_t i = ((size_t)blockIdx.x * 256 + threadIdx.x) * 4;
    f32x4 v = *(const f32x4*)(m + i);
    int any = (v[0] != 0.f) || (v[1] != 0.f) || (v[2] != 0.f) || (v[3] != 0.f);
    if (__any(any)) { if ((threadIdx.x & 63) == 0) atomicOr(flag, 1); }
}

// ---------------- fp32 -> bf16 convert (hidden) ----------------
__global__ void convH_k(const float* __restrict__ x, unsigned short* __restrict__ y) {
    size_t i = (size_t)blockIdx.x * 256 + threadIdx.x;
    f32x4 a = *(const f32x4*)(x + i * 8);
    f32x4 b = *(const f32x4*)(x + i * 8 + 4);
    u16x8 o;
    o[0] = f2bf(a[0]); o[1] = f2bf(a[1]); o[2] = f2bf(a[2]); o[3] = f2bf(a[3]);
    o[4] = f2bf(b[0]); o[5] = f2bf(b[1]); o[6] = f2bf(b[2]); o[7] = f2bf(b[3]);
    *(u16x8*)(y + i * 8) = o;
}

// ---------------- fp32 -> bf16 transpose (weights: W[R][C] -> Wt[C][R]) ----------------
__global__ void convT_k(const float* __restrict__ W, unsigned short* __restrict__ Wt,
                        int R, int C) {
    __shared__ float tile[32][33];
    int c0 = blockIdx.x * 32, r0 = blockIdx.y * 32;
    int t = threadIdx.x;
    int rr = t >> 3, cc = (t & 7) * 4;
    f32x4 v = *(const f32x4*)(W + (size_t)(r0 + rr) * C + c0 + cc);
    tile[rr][cc + 0] = v[0]; tile[rr][cc + 1] = v[1];
    tile[rr][cc + 2] = v[2]; tile[rr][cc + 3] = v[3];
    __syncthreads();
    u16x4 o;
    o[0] = f2bf(tile[cc + 0][rr]); o[1] = f2bf(tile[cc + 1][rr]);
    o[2] = f2bf(tile[cc + 2][rr]); o[3] = f2bf(tile[cc + 3][rr]);
    *(u16x4*)(Wt + (size_t)(c0 + rr) * R + r0 + cc) = o;
}

// ============ 128x256 GEMM, BK=64, 8 waves (2Mx4N, wave 64x64), dbuf 96KB ============
// C[M][N] = A[M][K] * Bt[N][K]^T bf16. Grid divides machine exactly:
// QKV 32x24=768 = 3 rounds of 256 CUs; outproj 32x8=256 = 1 round.
// LDS planes per buf (48KB): [A-kh0 8K][A-kh1 8K][B-kh0 16K][B-kh1 16K], rows of
// 64B, slot-XOR c^((row>>1)&3) -> 8 distinct 4-bank windows x2 lanes = free.
// Uniform 4-phase loop: each phase reads one (buf,kh), stages one plane-pair
// (3 gl16), vmcnt(6) at end (forces loads from 2 phases ago; read 3 phases
// after stage). Never vmcnt(0) in loop.
template<int MODE>
__global__ __launch_bounds__(512, 2)
void gemm128x256_k(const unsigned short* __restrict__ A, const unsigned short* __restrict__ Bt,
                   float* __restrict__ Cf, unsigned short* __restrict__ Cb,
                   int M, int N, int K) {
    __shared__ char lds[98304];
    int t = threadIdx.x, w = t >> 6, ln = t & 63, lr = ln & 15, lg = ln >> 4;
    int wm = w >> 2, wn = w & 3;
    int f = blockIdx.x, cpx = gridDim.x >> 3;
    int s = (f & 7) * cpx + (f >> 3);      // bijective XCD swizzle (grid % 8 == 0)
    int nbn = N >> 8;
    int nb = s % nbn, mb = s / nbn;
    int m0 = mb * 128, n0 = nb * 256;
    const char* Ab = (const char*)A;
    const char* Bbp = (const char*)Bt;

    f32x4 acc[4][4];
#pragma unroll
    for (int i = 0; i < 4; ++i)
#pragma unroll
        for (int j = 0; j < 4; ++j) { acc[i][j][0] = 0.f; acc[i][j][1] = 0.f; acc[i][j][2] = 0.f; acc[i][j][3] = 0.f; }

    // stage A-plane (8KB, 1 gl16/thr) of (sbuf, skh) from K-tile kt
    auto STGA = [&](int sbuf, int skh, int kt) {
        int row = t >> 2, c = t & 3;
        int cs = c ^ ((row >> 1) & 3);
        gl16(Ab + ((size_t)(m0 + row) * K + kt * 64 + skh * 32) * 2 + cs * 16,
             lds + sbuf * 49152 + skh * 8192 + t * 16);
    };
    // stage B-plane (16KB, 2 gl16/thr)
    auto STGB = [&](int sbuf, int skh, int kt) {
#pragma unroll
        for (int rr = 0; rr < 2; ++rr) {
            int ci = rr * 512 + t;
            int row = ci >> 2, c = ci & 3;
            int cs = c ^ ((row >> 1) & 3);
            gl16(Bbp + ((size_t)(n0 + row) * K + kt * 64 + skh * 32) * 2 + cs * 16,
                 lds + sbuf * 49152 + 16384 + skh * 16384 + ci * 16);
        }
    };

#define PH128(buf, kh, sbuf, skh, st)                                             \
  {                                                                               \
    const char* Ap = lds + (buf) * 49152 + (kh) * 8192;                           \
    const char* Bp = lds + (buf) * 49152 + 16384 + (kh) * 16384;                  \
    s16x8 af[4], bfr[4];                                                          \
    _Pragma("unroll")                                                             \
    for (int i = 0; i < 4; ++i) {                                                 \
      int row = wm * 64 + i * 16 + lr;                                            \
      af[i] = *(const s16x8*)(Ap + row * 64 + ((lg ^ ((row >> 1) & 3)) * 16));    \
    }                                                                             \
    _Pragma("unroll")                                                             \
    for (int j = 0; j < 4; ++j) {                                                 \
      int row = wn * 64 + j * 16 + lr;                                            \
      bfr[j] = *(const s16x8*)(Bp + row * 64 + ((lg ^ ((row >> 1) & 3)) * 16));   \
    }                                                                             \
    STGA(sbuf, skh, st); STGB(sbuf, skh, st);                                     \
    __builtin_amdgcn_s_barrier();                                                 \
    asm volatile("s_waitcnt lgkmcnt(0)" ::: "memory");                            \
    __builtin_amdgcn_s_setprio(1);                                                \
    _Pragma("unroll")                                                             \
    for (int i = 0; i < 4; ++i)                                                   \
      _Pragma("unroll")                                                           \
      for (int j = 0; j < 4; ++j)                                                 \
        acc[i][j] = __builtin_amdgcn_mfma_f32_16x16x32_bf16(af[i], bfr[j],        \
                                                            acc[i][j], 0, 0, 0); \
    __builtin_amdgcn_s_setprio(0);                                                \
    asm volatile("s_waitcnt vmcnt(6)" ::: "memory");                              \
    __builtin_amdgcn_s_barrier();                                                 \
  }

    const int NT = K >> 6;
    // prologue: b0 both kh @ tile0 (6 loads) + b1 kh0 @ tile1 (3 loads)
    STGA(0, 0, 0); STGB(0, 0, 0);
    STGA(0, 1, 0); STGB(0, 1, 0);
    STGA(1, 0, 1); STGB(1, 0, 1);
    asm volatile("s_waitcnt vmcnt(3)" ::: "memory");   // b0 fully landed
    __builtin_amdgcn_s_barrier();

    for (int it = 0; it < (NT >> 1); ++it) {
        int e = it * 2;
        int e2 = (e + 2 < NT) ? e + 2 : e;       // tail clamp: rewrite dead plane
        int e3 = (e + 3 < NT) ? e + 3 : e + 1;
        PH128(0, 0,  1, 1, e + 1)   // read b0.kh0; stage b1.kh1 @ e+1 (read p4)
        PH128(0, 1,  0, 0, e2)      // read b0.kh1; stage b0.kh0 @ e+2 (read p1')
        PH128(1, 0,  0, 1, e2)      // read b1.kh0; stage b0.kh1 @ e+2 (read p2')
        PH128(1, 1,  1, 0, e3)      // read b1.kh1; stage b1.kh0 @ e+3 (read p3')
    }
    asm volatile("s_waitcnt vmcnt(0)" ::: "memory");   // drain before exit
#undef PH128

    // fused RoPE (QKV only): wn even waves hold the rotary pair (j=0 -> d=lr,
    // j=1 -> d=lr+16) of each head's first half.
    if (MODE == 0 && n0 < 4096 && (wn & 1) == 0) {
        float invf = fexp2((float)lr * -0.83048202372f); // 10000^(-lr/16)
#pragma unroll
        for (int i = 0; i < 4; ++i)
#pragma unroll
            for (int r = 0; r < 4; ++r) {
                int srow = (m0 + wm * 64 + i * 16 + lg * 4 + r) & (Ss - 1);
                float sn, cs;
                sincosf((float)srow * invf, &sn, &cs);
                float x1 = acc[i][0][r], x2 = acc[i][1][r];
                acc[i][0][r] = x1 * cs - x2 * sn;
                acc[i][1][r] = x2 * cs + x1 * sn;
            }
    }

    // epilogue: C/D layout col=l&15, row=(l>>4)*4+r
#pragma unroll
    for (int i = 0; i < 4; ++i)
#pragma unroll
        for (int j = 0; j < 4; ++j)
#pragma unroll
            for (int r = 0; r < 4; ++r) {
                int gr = m0 + wm * 64 + i * 16 + lg * 4 + r;
                int gc = n0 + wn * 64 + j * 16 + lr;
                float vv = acc[i][j][r];
                if (MODE == 1) Cf[(size_t)gr * N + gc] = vv;
                else           Cb[(size_t)gr * N + gc] = f2bf(vv);
            }
}

// ---------------- V transpose: qkv v-part -> Vt[bh][d][s] ----------------
__global__ void vtrans_k(const unsigned short* __restrict__ qkv, unsigned short* __restrict__ Vt) {
    __shared__ unsigned short tile[64][40];
    int bh = blockIdx.x; int b = bh >> 4, h = bh & 15;
    int s0 = blockIdx.y * 64, d0 = blockIdx.z * 32;
    int t = threadIdx.x;
    int r = t >> 2, c8 = (t & 3) * 8;
    u16x8 v = *(const u16x8*)(qkv + ((size_t)(b * Ss + s0 + r)) * 6144 + 4096 + h * 128 + d0 + c8);
#pragma unroll
    for (int e = 0; e < 8; ++e) tile[r][c8 + e] = v[e];
    __syncthreads();
    int dr = t >> 3, sc = (t & 7) * 8;
    u16x8 o;
#pragma unroll
    for (int e = 0; e < 8; ++e) o[e] = tile[sc + e][dr];
    *(u16x8*)(Vt + ((size_t)bh * HD + d0 + dr) * Ss + s0 + sc) = o;
}

// ---------------- flash attention (R10 structure: dbuf K/V, overlapped staging) -------
__global__ __launch_bounds__(512)
void attn_k(const unsigned short* __restrict__ qkv, const unsigned short* __restrict__ Vt,
            const float* __restrict__ mask, unsigned short* __restrict__ ctxb,
            const int* __restrict__ flag) {
    __shared__ char ldsK[2][16384];            // [64 kk][128 d] bf16, swizzled
    __shared__ char ldsV[2][16384];            // [128 d][64 kk] bf16, swizzled
    __shared__ unsigned short ldsP[8][1024];   // per-wave P [16 q][64 kk], swizzled
    int f = blockIdx.x;
    int swzb = (f & 7) * 64 + (f >> 3);        // XCD swizzle
    int bh = swzb >> 4, qt = swzb & 15;
    int b = bh >> 4, h = bh & 15;
    int t = threadIdx.x, w = t >> 6, ln = t & 63, lr = ln & 15, lg = ln >> 4;
    int useMask = *flag;
    int qw0 = qt * 128 + w * 16;
    const char* qkvB = (const char*)qkv;
    const char* VtB = (const char*)Vt;

    auto STAGE = [&](int buf, int kk0s) {
#pragma unroll
        for (int c = 0; c < 2; ++c) {
            int ci = c * 512 + t;
            int krow = ci >> 4, kcb = (ci & 15) << 4;
            gl16(qkvB + (((size_t)(b * Ss + kk0s + krow)) * 6144 + 2048 + h * 128) * 2 + (kcb ^ ((krow & 7) << 4)),
                 ldsK[buf] + ci * 16);
            int vrow = ci >> 3, vcb = (ci & 7) << 4;
            gl16(VtB + (((size_t)(bh * 128 + vrow)) * 2048 + kk0s) * 2 + (vcb ^ ((vrow & 7) << 4)),
                 ldsV[buf] + ci * 16);
        }
    };

    s16x8 qf[4];
    size_t qbase = ((size_t)(b * Ss + qw0 + lr)) * 6144 + h * 128;
#pragma unroll
    for (int kc = 0; kc < 4; ++kc) qf[kc] = *(const s16x8*)(qkv + qbase + kc * 32 + lg * 8);

    float mr = -3e38f, lsum = 0.f;
    f32x4 ctxa[8];
#pragma unroll
    for (int dn = 0; dn < 8; ++dn) { ctxa[dn][0] = 0.f; ctxa[dn][1] = 0.f; ctxa[dn][2] = 0.f; ctxa[dn][3] = 0.f; }
    const float* mrow = mask + (size_t)b * Ss * Ss;

    STAGE(0, 0);
    asm volatile("s_waitcnt vmcnt(0)" ::: "memory");
    __builtin_amdgcn_s_barrier();

    for (int tix = 0; tix < 32; ++tix) {
        int kk0 = tix * 64;
        int cur = tix & 1;
        if (kk0 + 64 < Ss) STAGE(cur ^ 1, kk0 + 64);   // uniform branch

        f32x4 st[4];
#pragma unroll
        for (int n = 0; n < 4; ++n) {
            f32x4 sacc = {0.f, 0.f, 0.f, 0.f};
            const char* kb = ldsK[cur] + (n * 16 + lr) * 256;
            int sw = (lr & 7) << 4;
            s16x8 kf0 = *(const s16x8*)(kb + ((0 * 64 + lg * 16) ^ sw));
            s16x8 kf1 = *(const s16x8*)(kb + ((1 * 64 + lg * 16) ^ sw));
            s16x8 kf2 = *(const s16x8*)(kb + ((2 * 64 + lg * 16) ^ sw));
            s16x8 kf3 = *(const s16x8*)(kb + ((3 * 64 + lg * 16) ^ sw));
            __builtin_amdgcn_s_setprio(1);
            sacc = __builtin_amdgcn_mfma_f32_16x16x32_bf16(kf0, qf[0], sacc, 0, 0, 0);
            sacc = __builtin_amdgcn_mfma_f32_16x16x32_bf16(kf1, qf[1], sacc, 0, 0, 0);
            sacc = __builtin_amdgcn_mfma_f32_16x16x32_bf16(kf2, qf[2], sacc, 0, 0, 0);
            sacc = __builtin_amdgcn_mfma_f32_16x16x32_bf16(kf3, qf[3], sacc, 0, 0, 0);
            __builtin_amdgcn_s_setprio(0);
            st[n] = sacc;
        }
        if (useMask) {
#pragma unroll
            for (int n = 0; n < 4; ++n)
#pragma unroll
                for (int r = 0; r < 4; ++r)
                    st[n][r] += mrow[(size_t)(qw0 + lr) * Ss + kk0 + n * 16 + lg * 4 + r] * INV_SCALE;
        }
        float pmax = st[0][0];
#pragma unroll
        for (int n = 0; n < 4; ++n)
#pragma unroll
            for (int r = 0; r < 4; ++r) pmax = fmaxf(pmax, st[n][r]);
        pmax = fmaxf(pmax, __shfl_xor(pmax, 16));
        pmax = fmaxf(pmax, __shfl_xor(pmax, 32));
        bool need = pmax > mr + RAW_THR;
        if (__any(need)) {
            float mn = fmaxf(mr, pmax);
            float al = fexp2((mr - mn) * CEXP);
            mr = mn;
            lsum *= al;
            float a0 = __shfl(al, lg * 4 + 0), a1 = __shfl(al, lg * 4 + 1);
            float a2 = __shfl(al, lg * 4 + 2), a3 = __shfl(al, lg * 4 + 3);
#pragma unroll
            for (int dn = 0; dn < 8; ++dn) {
                ctxa[dn][0] *= a0; ctxa[dn][1] *= a1; ctxa[dn][2] *= a2; ctxa[dn][3] *= a3;
            }
        }
        float mC = mr * CEXP;
        float rs = 0.f;
        u16x4 pk[4];
#pragma unroll
        for (int n = 0; n < 4; ++n)
#pragma unroll
            for (int r = 0; r < 4; ++r) {
                float p = fexp2(st[n][r] * CEXP - mC);
                rs += p;
                pk[n][r] = f2bf(p);
            }
        rs += __shfl_xor(rs, 16);
        rs += __shfl_xor(rs, 32);
        lsum += rs;
        char* pw = (char*)ldsP[w];
        int swp = (lr & 7) << 4;
#pragma unroll
        for (int n = 0; n < 4; ++n)
            *(u16x4*)(pw + lr * 128 + ((32 * n + 8 * lg) ^ swp)) = pk[n];
        asm volatile("s_waitcnt lgkmcnt(0)" ::: "memory");
        s16x8 pa[2];
#pragma unroll
        for (int c2 = 0; c2 < 2; ++c2)
            pa[c2] = *(const s16x8*)(pw + lr * 128 + ((64 * c2 + 16 * lg) ^ swp));
#pragma unroll
        for (int dn = 0; dn < 8; ++dn) {
            const char* vb = ldsV[cur] + (dn * 16 + lr) * 128;
            s16x8 vf0 = *(const s16x8*)(vb + ((0 * 64 + lg * 16) ^ swp));
            s16x8 vf1 = *(const s16x8*)(vb + ((1 * 64 + lg * 16) ^ swp));
            __builtin_amdgcn_s_setprio(1);
            ctxa[dn] = __builtin_amdgcn_mfma_f32_16x16x32_bf16(pa[0], vf0, ctxa[dn], 0, 0, 0);
            ctxa[dn] = __builtin_amdgcn_mfma_f32_16x16x32_bf16(pa[1], vf1, ctxa[dn], 0, 0, 0);
            __builtin_amdgcn_s_setprio(0);
        }
        asm volatile("s_waitcnt vmcnt(0)" ::: "memory");
        __builtin_amdgcn_s_barrier();
    }
    float l0 = 1.f / __shfl(lsum, lg * 4 + 0), l1 = 1.f / __shfl(lsum, lg * 4 + 1);
    float l2 = 1.f / __shfl(lsum, lg * 4 + 2), l3 = 1.f / __shfl(lsum, lg * 4 + 3);
#pragma unroll
    for (int dn = 0; dn < 8; ++dn) {
        size_t base = ((size_t)(b * Ss + qw0)) * Hh + h * 128 + dn * 16 + lr;
        ctxb[base + (size_t)(lg * 4 + 0) * Hh] = f2bf(ctxa[dn][0] * l0);
        ctxb[base + (size_t)(lg * 4 + 1) * Hh] = f2bf(ctxa[dn][1] * l1);
        ctxb[base + (size_t)(lg * 4 + 2) * Hh] = f2bf(ctxa[dn][2] * l2);
        ctxb[base + (size_t)(lg * 4 + 3) * Hh] = f2bf(ctxa[dn][3] * l3);
    }
}

extern "C" void kernel_launch(void* const* d_in, const int* in_sizes, int n_in,
                              void* d_out, int out_size, void* d_ws, size_t ws_size,
                              hipStream_t stream) {
    (void)in_sizes; (void)n_in; (void)out_size; (void)ws_size;
    const float* hidden = (const float*)d_in[0];
    const float* mask   = (const float*)d_in[1];
    const float* Wqkv   = (const float*)d_in[2];
    const float* Wout   = (const float*)d_in[3];
    float* out = (float*)d_out;

    char* ws = (char*)d_ws;
    size_t off = 0;
    auto alloc = [&](size_t bytes) { char* p = ws + off; off += (bytes + 255) & ~(size_t)255; return p; };
    unsigned short* hbf   = (unsigned short*)alloc((size_t)8388608 * 2);   // hidden bf16; later aliased as ctx
    unsigned short* wqkvT = (unsigned short*)alloc((size_t)12582912 * 2);  // (6144,2048)
    unsigned short* woutT = (unsigned short*)alloc((size_t)4194304 * 2);   // (2048,2048)
    unsigned short* qkv   = (unsigned short*)alloc((size_t)25165824 * 2);  // (4096,6144)
    unsigned short* Vt    = (unsigned short*)alloc((size_t)8388608 * 2);   // (32,128,2048)
    int* flag             = (int*)alloc(256);
    unsigned short* ctx = hbf; // alias: hidden bf16 dead after QKV GEMM

    zero_flag_k<<<1, 64, 0, stream>>>(flag);
    scan_mask_k<<<2048, 256, 0, stream>>>(mask, flag);
    convH_k<<<4096, 256, 0, stream>>>(hidden, hbf);
    convT_k<<<dim3(192, 64), 256, 0, stream>>>(Wqkv, wqkvT, 2048, 6144);
    convT_k<<<dim3(64, 64), 256, 0, stream>>>(Wout, woutT, 2048, 2048);
    gemm128x256_k<0><<<768, 512, 0, stream>>>(hbf, wqkvT, nullptr, qkv, 4096, 6144, 2048);
    vtrans_k<<<dim3(32, 32, 4), 256, 0, stream>>>(qkv, Vt);
    attn_k<<<512, 512, 0, stream>>>(qkv, Vt, mask, ctx, flag);
    gemm128x256_k<1><<<256, 512, 0, stream>>>(ctx, woutT, out, nullptr, 4096, 2048, 2048);
}

// Round 12
// 300.765 us; speedup vs baseline: 1.0272x; 1.0027x over previous
//
#include <hip/hip_runtime.h>

typedef __attribute__((ext_vector_type(4))) float f32x4;
typedef __attribute__((ext_vector_type(8))) short s16x8;
typedef __attribute__((ext_vector_type(4))) unsigned short u16x4;
typedef __attribute__((ext_vector_type(8))) unsigned short u16x8;

#define DEVINL __device__ __forceinline__

constexpr int Bb = 2;
constexpr int Ss = 2048;
constexpr int Hh = 2048;
constexpr int NH = 16;
constexpr int HD = 128;
constexpr float ATT_SCALE = 0.08838834764831845f;   // 128^-0.5
constexpr float CEXP = ATT_SCALE * 1.44269504089f;  // scale * log2(e)
constexpr float INV_SCALE = 11.313708498984761f;    // 1/scale
constexpr float RAW_THR = 90.50966799f;             // 8/scale (defer-max threshold)

DEVINL unsigned short f2bf(float f) {
    unsigned u = __float_as_uint(f);
    u += 0x7FFFu + ((u >> 16) & 1u);
    return (unsigned short)(u >> 16);
}
DEVINL float bf2f(unsigned short h) { return __uint_as_float(((unsigned)h) << 16); }
DEVINL float fexp2(float x) { return __builtin_amdgcn_exp2f(x); }

// global -> LDS direct (16B per lane). Dest must be linear in lane order.
DEVINL void gl16(const void* g, void* l) {
    __builtin_amdgcn_global_load_lds((const __attribute__((address_space(1))) void*)g,
                                     (__attribute__((address_space(3))) void*)l, 16, 0, 0);
}

// ---------------- mask zero-scan (full coverage: 8192 blocks x 1024 floats) ----------
__global__ void scan_mask_k(const float* __restrict__ m, int* __restrict__ flag) {
    size_t i = ((size_t)blockIdx.x * 256 + threadIdx.x) * 4;
    f32x4 v = *(const f32x4*)(m + i);
    int any = (v[0] != 0.f) || (v[1] != 0.f) || (v[2] != 0.f) || (v[3] != 0.f);
    if (__any(any)) { if ((threadIdx.x & 63) == 0) atomicOr(flag, 1); }
}

// ---------------- fp32 -> bf16 convert (hidden) ----------------
__global__ void convH_k(const float* __restrict__ x, unsigned short* __restrict__ y) {
    size_t i = (size_t)blockIdx.x * 256 + threadIdx.x;
    f32x4 a = *(const f32x4*)(x + i * 8);
    f32x4 b = *(const f32x4*)(x + i * 8 + 4);
    u16x8 o;
    o[0] = f2bf(a[0]); o[1] = f2bf(a[1]); o[2] = f2bf(a[2]); o[3] = f2bf(a[3]);
    o[4] = f2bf(b[0]); o[5] = f2bf(b[1]); o[6] = f2bf(b[2]); o[7] = f2bf(b[3]);
    *(u16x8*)(y + i * 8) = o;
}

// ---------------- fp32 -> bf16 transpose (weights: W[R][C] -> Wt[C][R]) ----------------
__global__ void convT_k(const float* __restrict__ W, unsigned short* __restrict__ Wt,
                        int R, int C) {
    __shared__ float tile[32][33];
    int c0 = blockIdx.x * 32, r0 = blockIdx.y * 32;
    int t = threadIdx.x;
    int rr = t >> 3, cc = (t & 7) * 4;
    f32x4 v = *(const f32x4*)(W + (size_t)(r0 + rr) * C + c0 + cc);
    tile[rr][cc + 0] = v[0]; tile[rr][cc + 1] = v[1];
    tile[rr][cc + 2] = v[2]; tile[rr][cc + 3] = v[3];
    __syncthreads();
    u16x4 o;
    o[0] = f2bf(tile[cc + 0][rr]); o[1] = f2bf(tile[cc + 1][rr]);
    o[2] = f2bf(tile[cc + 2][rr]); o[3] = f2bf(tile[cc + 3][rr]);
    *(u16x4*)(Wt + (size_t)(c0 + rr) * R + r0 + cc) = o;
}

// ============ 128x256 GEMM, BK=64, 8 waves (2Mx4N, wave 64x64), dbuf 96KB ============
// Rectangle XCD swizzle: each XCD owns a rm x rn patch of (mb,nb) tiles so its
// L2 working set is {rm A-panels + rn B-panels} instead of all of B.
// MODE 0 (QKV): fused RoPE on q/k rotary cols; V columns (n0>=4096) written
// TRANSPOSED into Vt[bh][d][s] (vtrans kernel eliminated; qkv V-part unwritten).
template<int MODE>
__global__ __launch_bounds__(512, 2)
void gemm128x256_k(const unsigned short* __restrict__ A, const unsigned short* __restrict__ Bt,
                   float* __restrict__ Cf, unsigned short* __restrict__ Cb,
                   unsigned short* __restrict__ VtOut,
                   int M, int N, int K, int rm, int rn, int snx) {
    __shared__ char lds[98304];
    int t = threadIdx.x, w = t >> 6, ln = t & 63, lr = ln & 15, lg = ln >> 4;
    int wm = w >> 2, wn = w & 3;
    int f = blockIdx.x;
    int xcd = f & 7, i0 = f >> 3;
    int mb = (xcd / snx) * rm + i0 % rm;
    int nb = (xcd % snx) * rn + i0 / rm;
    int m0 = mb * 128, n0 = nb * 256;
    const char* Ab = (const char*)A;
    const char* Bbp = (const char*)Bt;

    f32x4 acc[4][4];
#pragma unroll
    for (int i = 0; i < 4; ++i)
#pragma unroll
        for (int j = 0; j < 4; ++j) { acc[i][j][0] = 0.f; acc[i][j][1] = 0.f; acc[i][j][2] = 0.f; acc[i][j][3] = 0.f; }

    // stage A-plane (8KB, 1 gl16/thr) of (sbuf, skh) from K-tile kt
    auto STGA = [&](int sbuf, int skh, int kt) {
        int row = t >> 2, c = t & 3;
        int cs = c ^ ((row >> 1) & 3);
        gl16(Ab + ((size_t)(m0 + row) * K + kt * 64 + skh * 32) * 2 + cs * 16,
             lds + sbuf * 49152 + skh * 8192 + t * 16);
    };
    // stage B-plane (16KB, 2 gl16/thr)
    auto STGB = [&](int sbuf, int skh, int kt) {
#pragma unroll
        for (int rr = 0; rr < 2; ++rr) {
            int ci = rr * 512 + t;
            int row = ci >> 2, c = ci & 3;
            int cs = c ^ ((row >> 1) & 3);
            gl16(Bbp + ((size_t)(n0 + row) * K + kt * 64 + skh * 32) * 2 + cs * 16,
                 lds + sbuf * 49152 + 16384 + skh * 16384 + ci * 16);
        }
    };

#define PH128(buf, kh, sbuf, skh, st)                                             \
  {                                                                               \
    const char* Ap = lds + (buf) * 49152 + (kh) * 8192;                           \
    const char* Bp = lds + (buf) * 49152 + 16384 + (kh) * 16384;                  \
    s16x8 af[4], bfr[4];                                                          \
    _Pragma("unroll")                                                             \
    for (int i = 0; i < 4; ++i) {                                                 \
      int row = wm * 64 + i * 16 + lr;                                            \
      af[i] = *(const s16x8*)(Ap + row * 64 + ((lg ^ ((row >> 1) & 3)) * 16));    \
    }                                                                             \
    _Pragma("unroll")                                                             \
    for (int j = 0; j < 4; ++j) {                                                 \
      int row = wn * 64 + j * 16 + lr;                                            \
      bfr[j] = *(const s16x8*)(Bp + row * 64 + ((lg ^ ((row >> 1) & 3)) * 16));   \
    }                                                                             \
    STGA(sbuf, skh, st); STGB(sbuf, skh, st);                                     \
    __builtin_amdgcn_s_barrier();                                                 \
    asm volatile("s_waitcnt lgkmcnt(0)" ::: "memory");                            \
    __builtin_amdgcn_s_setprio(1);                                                \
    _Pragma("unroll")                                                             \
    for (int i = 0; i < 4; ++i)                                                   \
      _Pragma("unroll")                                                           \
      for (int j = 0; j < 4; ++j)                                                 \
        acc[i][j] = __builtin_amdgcn_mfma_f32_16x16x32_bf16(af[i], bfr[j],        \
                                                            acc[i][j], 0, 0, 0); \
    __builtin_amdgcn_s_setprio(0);                                                \
    asm volatile("s_waitcnt vmcnt(6)" ::: "memory");                              \
    __builtin_amdgcn_s_barrier();                                                 \
  }

    const int NT = K >> 6;
    // prologue: b0 both kh @ tile0 (6 loads) + b1 kh0 @ tile1 (3 loads)
    STGA(0, 0, 0); STGB(0, 0, 0);
    STGA(0, 1, 0); STGB(0, 1, 0);
    STGA(1, 0, 1); STGB(1, 0, 1);
    asm volatile("s_waitcnt vmcnt(3)" ::: "memory");   // b0 fully landed
    __builtin_amdgcn_s_barrier();

    for (int it = 0; it < (NT >> 1); ++it) {
        int e = it * 2;
        int e2 = (e + 2 < NT) ? e + 2 : e;       // tail clamp: rewrite dead plane
        int e3 = (e + 3 < NT) ? e + 3 : e + 1;
        PH128(0, 0,  1, 1, e + 1)   // read b0.kh0; stage b1.kh1 @ e+1 (read p4)
        PH128(0, 1,  0, 0, e2)      // read b0.kh1; stage b0.kh0 @ e+2 (read p1')
        PH128(1, 0,  0, 1, e2)      // read b1.kh0; stage b0.kh1 @ e+2 (read p2')
        PH128(1, 1,  1, 0, e3)      // read b1.kh1; stage b1.kh0 @ e+3 (read p3')
    }
    asm volatile("s_waitcnt vmcnt(0)" ::: "memory");   // drain before exit
#undef PH128

    if (MODE == 0 && n0 >= 4096) {
        // V columns: write transposed directly into Vt[bh=(b*16+h)][d][s]
#pragma unroll
        for (int i = 0; i < 4; ++i)
#pragma unroll
            for (int j = 0; j < 4; ++j) {
                int vcol = n0 - 4096 + wn * 64 + j * 16 + lr;   // 0..2047
                int h = vcol >> 7, d = vcol & 127;
                int gr = m0 + wm * 64 + i * 16 + lg * 4;
                int bb = gr >> 11, si = gr & 2047;
                u16x4 o;
                o[0] = f2bf(acc[i][j][0]); o[1] = f2bf(acc[i][j][1]);
                o[2] = f2bf(acc[i][j][2]); o[3] = f2bf(acc[i][j][3]);
                *(u16x4*)(VtOut + ((size_t)(bb * 16 + h) * 128 + d) * 2048 + si) = o;
            }
        return;
    }

    // fused RoPE (QKV only, n0 < 4096 here): wn even waves hold the rotary pair
    // (j=0 -> d=lr, j=1 -> d=lr+16) of each head's first half.
    if (MODE == 0 && (wn & 1) == 0) {
        float invf = fexp2((float)lr * -0.83048202372f); // 10000^(-lr/16)
#pragma unroll
        for (int i = 0; i < 4; ++i)
#pragma unroll
            for (int r = 0; r < 4; ++r) {
                int srow = (m0 + wm * 64 + i * 16 + lg * 4 + r) & (Ss - 1);
                float sn, cs;
                sincosf((float)srow * invf, &sn, &cs);
                float x1 = acc[i][0][r], x2 = acc[i][1][r];
                acc[i][0][r] = x1 * cs - x2 * sn;
                acc[i][1][r] = x2 * cs + x1 * sn;
            }
    }

    // epilogue: C/D layout col=l&15, row=(l>>4)*4+r
#pragma unroll
    for (int i = 0; i < 4; ++i)
#pragma unroll
        for (int j = 0; j < 4; ++j)
#pragma unroll
            for (int r = 0; r < 4; ++r) {
                int gr = m0 + wm * 64 + i * 16 + lg * 4 + r;
                int gc = n0 + wn * 64 + j * 16 + lr;
                float vv = acc[i][j][r];
                if (MODE == 1) Cf[(size_t)gr * N + gc] = vv;
                else           Cb[(size_t)gr * N + gc] = f2bf(vv);
            }
}

// ---------------- flash attention (R10 structure: dbuf K/V, overlapped staging) -------
__global__ __launch_bounds__(512)
void attn_k(const unsigned short* __restrict__ qkv, const unsigned short* __restrict__ Vt,
            const float* __restrict__ mask, unsigned short* __restrict__ ctxb,
            const int* __restrict__ flag) {
    __shared__ char ldsK[2][16384];            // [64 kk][128 d] bf16, swizzled
    __shared__ char ldsV[2][16384];            // [128 d][64 kk] bf16, swizzled
    __shared__ unsigned short ldsP[8][1024];   // per-wave P [16 q][64 kk], swizzled
    int f = blockIdx.x;
    int swzb = (f & 7) * 64 + (f >> 3);        // XCD swizzle
    int bh = swzb >> 4, qt = swzb & 15;
    int b = bh >> 4, h = bh & 15;
    int t = threadIdx.x, w = t >> 6, ln = t & 63, lr = ln & 15, lg = ln >> 4;
    int useMask = *flag;
    int qw0 = qt * 128 + w * 16;
    const char* qkvB = (const char*)qkv;
    const char* VtB = (const char*)Vt;

    auto STAGE = [&](int buf, int kk0s) {
#pragma unroll
        for (int c = 0; c < 2; ++c) {
            int ci = c * 512 + t;
            int krow = ci >> 4, kcb = (ci & 15) << 4;
            gl16(qkvB + (((size_t)(b * Ss + kk0s + krow)) * 6144 + 2048 + h * 128) * 2 + (kcb ^ ((krow & 7) << 4)),
                 ldsK[buf] + ci * 16);
            int vrow = ci >> 3, vcb = (ci & 7) << 4;
            gl16(VtB + (((size_t)(bh * 128 + vrow)) * 2048 + kk0s) * 2 + (vcb ^ ((vrow & 7) << 4)),
                 ldsV[buf] + ci * 16);
        }
    };

    s16x8 qf[4];
    size_t qbase = ((size_t)(b * Ss + qw0 + lr)) * 6144 + h * 128;
#pragma unroll
    for (int kc = 0; kc < 4; ++kc) qf[kc] = *(const s16x8*)(qkv + qbase + kc * 32 + lg * 8);

    float mr = -3e38f, lsum = 0.f;
    f32x4 ctxa[8];
#pragma unroll
    for (int dn = 0; dn < 8; ++dn) { ctxa[dn][0] = 0.f; ctxa[dn][1] = 0.f; ctxa[dn][2] = 0.f; ctxa[dn][3] = 0.f; }
    const float* mrow = mask + (size_t)b * Ss * Ss;

    STAGE(0, 0);
    asm volatile("s_waitcnt vmcnt(0)" ::: "memory");
    __builtin_amdgcn_s_barrier();

    for (int tix = 0; tix < 32; ++tix) {
        int kk0 = tix * 64;
        int cur = tix & 1;
        if (kk0 + 64 < Ss) STAGE(cur ^ 1, kk0 + 64);   // uniform branch

        f32x4 st[4];
#pragma unroll
        for (int n = 0; n < 4; ++n) {
            f32x4 sacc = {0.f, 0.f, 0.f, 0.f};
            const char* kb = ldsK[cur] + (n * 16 + lr) * 256;
            int sw = (lr & 7) << 4;
            s16x8 kf0 = *(const s16x8*)(kb + ((0 * 64 + lg * 16) ^ sw));
            s16x8 kf1 = *(const s16x8*)(kb + ((1 * 64 + lg * 16) ^ sw));
            s16x8 kf2 = *(const s16x8*)(kb + ((2 * 64 + lg * 16) ^ sw));
            s16x8 kf3 = *(const s16x8*)(kb + ((3 * 64 + lg * 16) ^ sw));
            __builtin_amdgcn_s_setprio(1);
            sacc = __builtin_amdgcn_mfma_f32_16x16x32_bf16(kf0, qf[0], sacc, 0, 0, 0);
            sacc = __builtin_amdgcn_mfma_f32_16x16x32_bf16(kf1, qf[1], sacc, 0, 0, 0);
            sacc = __builtin_amdgcn_mfma_f32_16x16x32_bf16(kf2, qf[2], sacc, 0, 0, 0);
            sacc = __builtin_amdgcn_mfma_f32_16x16x32_bf16(kf3, qf[3], sacc, 0, 0, 0);
            __builtin_amdgcn_s_setprio(0);
            st[n] = sacc;
        }
        if (useMask) {
#pragma unroll
            for (int n = 0; n < 4; ++n)
#pragma unroll
                for (int r = 0; r < 4; ++r)
                    st[n][r] += mrow[(size_t)(qw0 + lr) * Ss + kk0 + n * 16 + lg * 4 + r] * INV_SCALE;
        }
        float pmax = st[0][0];
#pragma unroll
        for (int n = 0; n < 4; ++n)
#pragma unroll
            for (int r = 0; r < 4; ++r) pmax = fmaxf(pmax, st[n][r]);
        pmax = fmaxf(pmax, __shfl_xor(pmax, 16));
        pmax = fmaxf(pmax, __shfl_xor(pmax, 32));
        bool need = pmax > mr + RAW_THR;
        if (__any(need)) {
            float mn = fmaxf(mr, pmax);
            float al = fexp2((mr - mn) * CEXP);
            mr = mn;
            lsum *= al;
            float a0 = __shfl(al, lg * 4 + 0), a1 = __shfl(al, lg * 4 + 1);
            float a2 = __shfl(al, lg * 4 + 2), a3 = __shfl(al, lg * 4 + 3);
#pragma unroll
            for (int dn = 0; dn < 8; ++dn) {
                ctxa[dn][0] *= a0; ctxa[dn][1] *= a1; ctxa[dn][2] *= a2; ctxa[dn][3] *= a3;
            }
        }
        float mC = mr * CEXP;
        float rs = 0.f;
        u16x4 pk[4];
#pragma unroll
        for (int n = 0; n < 4; ++n)
#pragma unroll
            for (int r = 0; r < 4; ++r) {
                float p = fexp2(st[n][r] * CEXP - mC);
                rs += p;
                pk[n][r] = f2bf(p);
            }
        rs += __shfl_xor(rs, 16);
        rs += __shfl_xor(rs, 32);
        lsum += rs;
        char* pw = (char*)ldsP[w];
        int swp = (lr & 7) << 4;
#pragma unroll
        for (int n = 0; n < 4; ++n)
            *(u16x4*)(pw + lr * 128 + ((32 * n + 8 * lg) ^ swp)) = pk[n];
        asm volatile("s_waitcnt lgkmcnt(0)" ::: "memory");
        s16x8 pa[2];
#pragma unroll
        for (int c2 = 0; c2 < 2; ++c2)
            pa[c2] = *(const s16x8*)(pw + lr * 128 + ((64 * c2 + 16 * lg) ^ swp));
#pragma unroll
        for (int dn = 0; dn < 8; ++dn) {
            const char* vb = ldsV[cur] + (dn * 16 + lr) * 128;
            s16x8 vf0 = *(const s16x8*)(vb + ((0 * 64 + lg * 16) ^ swp));
            s16x8 vf1 = *(const s16x8*)(vb + ((1 * 64 + lg * 16) ^ swp));
            __builtin_amdgcn_s_setprio(1);
            ctxa[dn] = __builtin_amdgcn_mfma_f32_16x16x32_bf16(pa[0], vf0, ctxa[dn], 0, 0, 0);
            ctxa[dn] = __builtin_amdgcn_mfma_f32_16x16x32_bf16(pa[1], vf1, ctxa[dn], 0, 0, 0);
            __builtin_amdgcn_s_setprio(0);
        }
        asm volatile("s_waitcnt vmcnt(0)" ::: "memory");
        __builtin_amdgcn_s_barrier();
    }
    float l0 = 1.f / __shfl(lsum, lg * 4 + 0), l1 = 1.f / __shfl(lsum, lg * 4 + 1);
    float l2 = 1.f / __shfl(lsum, lg * 4 + 2), l3 = 1.f / __shfl(lsum, lg * 4 + 3);
#pragma unroll
    for (int dn = 0; dn < 8; ++dn) {
        size_t base = ((size_t)(b * Ss + qw0)) * Hh + h * 128 + dn * 16 + lr;
        ctxb[base + (size_t)(lg * 4 + 0) * Hh] = f2bf(ctxa[dn][0] * l0);
        ctxb[base + (size_t)(lg * 4 + 1) * Hh] = f2bf(ctxa[dn][1] * l1);
        ctxb[base + (size_t)(lg * 4 + 2) * Hh] = f2bf(ctxa[dn][2] * l2);
        ctxb[base + (size_t)(lg * 4 + 3) * Hh] = f2bf(ctxa[dn][3] * l3);
    }
}

extern "C" void kernel_launch(void* const* d_in, const int* in_sizes, int n_in,
                              void* d_out, int out_size, void* d_ws, size_t ws_size,
                              hipStream_t stream) {
    (void)in_sizes; (void)n_in; (void)out_size; (void)ws_size;
    const float* hidden = (const float*)d_in[0];
    const float* mask   = (const float*)d_in[1];
    const float* Wqkv   = (const float*)d_in[2];
    const float* Wout   = (const float*)d_in[3];
    float* out = (float*)d_out;

    char* ws = (char*)d_ws;
    size_t off = 0;
    auto alloc = [&](size_t bytes) { char* p = ws + off; off += (bytes + 255) & ~(size_t)255; return p; };
    unsigned short* hbf   = (unsigned short*)alloc((size_t)8388608 * 2);   // hidden bf16; later aliased as ctx
    unsigned short* wqkvT = (unsigned short*)alloc((size_t)12582912 * 2);  // (6144,2048)
    unsigned short* woutT = (unsigned short*)alloc((size_t)4194304 * 2);   // (2048,2048)
    unsigned short* qkv   = (unsigned short*)alloc((size_t)25165824 * 2);  // (4096,6144); V third unused
    unsigned short* Vt    = (unsigned short*)alloc((size_t)8388608 * 2);   // (32,128,2048)
    int* flag             = (int*)alloc(256);
    unsigned short* ctx = hbf; // alias: hidden bf16 dead after QKV GEMM

    hipMemsetAsync(flag, 0, 4, stream);
    scan_mask_k<<<8192, 256, 0, stream>>>(mask, flag);
    convH_k<<<4096, 256, 0, stream>>>(hidden, hbf);
    convT_k<<<dim3(192, 64), 256, 0, stream>>>(Wqkv, wqkvT, 2048, 6144);
    convT_k<<<dim3(64, 64), 256, 0, stream>>>(Wout, woutT, 2048, 2048);
    gemm128x256_k<0><<<768, 512, 0, stream>>>(hbf, wqkvT, nullptr, qkv, Vt,
                                              4096, 6144, 2048, 16, 6, 4);
    attn_k<<<512, 512, 0, stream>>>(qkv, Vt, mask, ctx, flag);
    gemm128x256_k<1><<<256, 512, 0, stream>>>(ctx, woutT, out, nullptr, nullptr,
                                              4096, 2048, 2048, 16, 2, 4);
}